// Round 9
// baseline (92.032 us; speedup 1.0000x reference)
//
#include <hip/hip_runtime.h>

// Simple_TensorProduct (e3nn uvw TP, MUL=256, l<=1, v=1) as two fused bf16 GEMMs.
//   out0[z,w]      = sum_k T0[z,k]    * B0[k,w]   (K=512)
//   out1[(z,c),w]  = sum_k T1[(z,c),k]* B1[k,w]   (K=768, M=3N)
// T = x1 with x2 folded in (built per z-tile, bf16, LDS, A-fragment order).
// B = weights, prescaled by path alphas, bf16, B-fragment order in d_ws.
//
// R9 = R8 with the nontemporal builtin applied through a native clang
// vector type (ext_vector_type), which __builtin_nontemporal_load requires.
//  (1) x1 loaded with nt hint: x1 streams once; keeping it out of L2
//      preserves the 640KB B working set -> B loads are L2 hits.
//  (2) odd blocks process u-chunks in order (1,0): phase/address diversity.
// Build/gemm/epilogue math identical to R2.

typedef short bf16x8 __attribute__((ext_vector_type(8)));
typedef float f32x4 __attribute__((ext_vector_type(4)));
typedef float nf4 __attribute__((ext_vector_type(4)));   // native vec for nt builtins

static __device__ __forceinline__ unsigned short f2bf(float f) {
  unsigned int u = __builtin_bit_cast(unsigned int, f);
  u += 0x7FFFu + ((u >> 16) & 1u);   // RNE
  return (unsigned short)(u >> 16);
}

static __device__ __forceinline__ bf16x8 asbf(int4 v) {
  return __builtin_bit_cast(bf16x8, v);
}

static __device__ __forceinline__ float4 ntld(const float* p) {
  nf4 v = __builtin_nontemporal_load((const nf4*)p);
  return __builtin_bit_cast(float4, v);
}

// ---------------------------------------------------------------------------
// Weight prep: fp32 weights -> prescaled bf16 in MFMA B-operand fragment order.
// B1 region: frag id ((c*12+kt)*16+ct)*64+lane   (24576 frags, 393216 B)
// B0 region: frag id 24576 + ((c*8+kt)*16+ct)*64+lane (16384 frags, 262144 B)
// element e of a frag: k_chunk = kt*32 + (lane>>4)*8 + e, w = ct*16 + (lane&15)
// chunk c covers u in [128c, 128c+128).
// ---------------------------------------------------------------------------
__global__ __launch_bounds__(256) void prep_weights(
    const float* __restrict__ wgt, unsigned short* __restrict__ Bw)
{
  int fid = blockIdx.x * 256 + threadIdx.x;
  union { unsigned short h[8]; int4 v; } pk;
  if (fid < 24576) {
    // B1: seg0->W2*(A1/sqrt3), seg1->W3*(A1/sqrt3), seg2->W5*(A1/sqrt6)
    int lane = fid & 63;
    int ct = (fid >> 6) & 15;
    int q = fid >> 10;            // 0..23
    int kt = q % 12, c = q / 12;
    int w = ct * 16 + (lane & 15);
    int kh = (lane >> 4) * 8;
#pragma unroll
    for (int e = 0; e < 8; ++e) {
      int kc = kt * 32 + kh + e;       // 0..383
      int seg = kc >> 7;
      int u = c * 128 + (kc & 127);
      float s  = (seg == 2) ? 0.025515518153991442f : 0.03608439182435161f;
      int off  = (seg == 0) ? 65536 : (seg == 1 ? 131072 : 262144);
      pk.h[e] = f2bf(wgt[off + u * 256 + w] * s);
    }
    ((int4*)Bw)[fid] = pk.v;
  } else if (fid < 40960) {
    // B0: seg0->W1*A0, seg1->W4*(A0/sqrt3)
    int f2 = fid - 24576;
    int lane = f2 & 63;
    int ct = (f2 >> 6) & 15;
    int q = f2 >> 10;             // 0..15
    int kt = q & 7, c = q >> 3;
    int w = ct * 16 + (lane & 15);
    int kh = (lane >> 4) * 8;
#pragma unroll
    for (int e = 0; e < 8; ++e) {
      int kc = kt * 32 + kh + e;       // 0..255
      int seg = kc >> 7;
      int u = c * 128 + (kc & 127);
      float s  = (seg == 0) ? 0.04419417382415922f : 0.025515518153991442f;
      int off  = (seg == 0) ? 0 : 196608;
      pk.h[e] = f2bf(wgt[off + u * 256 + w] * s);
    }
    ((int4*)Bw)[fid] = pk.v;
  }
}

#define T0BASE 2304

struct X1Regs {
  float4 s[2];   // s1[u .. u+8)
  float4 v[6];   // v1[(u..u+8), 0..3) interleaved: f[3e+k]
};

static __device__ __forceinline__ void load_x1(
    X1Regs& r, const float* __restrict__ x1, int zrow, int ub, int rr)
{
  const float* base = x1 + (size_t)zrow * 1024;
  const float* ps = base + ub + rr * 8;
  r.s[0] = ntld(ps); r.s[1] = ntld(ps + 4);
  const float* pv = base + 256 + 3 * ub + rr * 24;
#pragma unroll
  for (int i = 0; i < 6; ++i) r.v[i] = ntld(pv + 4 * i);
}

static __device__ __forceinline__ void build_frags(
    const X1Regs& r, int zl, int rr, float s2, const float* v2, int4* ldsT)
{
  union { float4 q[2]; float f[8]; } s1u;
  s1u.q[0] = r.s[0]; s1u.q[1] = r.s[1];
  union { float4 q[6]; float f[24]; } v1u;
#pragma unroll
  for (int i = 0; i < 6; ++i) v1u.q[i] = r.v[i];
  const int lh = rr & 3;
  const int kq = rr >> 2;

  // ---- T1: seg 0..2 x comp k 0..2 ; row = 3*zl + k
#pragma unroll
  for (int sg = 0; sg < 3; ++sg) {
#pragma unroll
    for (int k = 0; k < 3; ++k) {
      int row = 3 * zl + k;
      int kt  = sg * 4 + kq;
      int fl  = (((lh << 4) | (row & 15)) ^ (kt & 7)) ^ lh;
      int addr = (row >> 4) * 768 + kt * 64 + fl;
      float t[8];
      if (sg == 0) {                     // s1 * v2[k]      (-> W2)
#pragma unroll
        for (int e = 0; e < 8; ++e) t[e] = s1u.f[e] * v2[k];
      } else if (sg == 1) {              // v1[.,k] * s2    (-> W3)
#pragma unroll
        for (int e = 0; e < 8; ++e) t[e] = v1u.f[3 * e + k] * s2;
      } else {                           // (v1 x v2)[k]    (-> W5)
        int k1 = k + 1; if (k1 > 2) k1 -= 3;
        int k2 = k + 2; if (k2 > 2) k2 -= 3;
#pragma unroll
        for (int e = 0; e < 8; ++e)
          t[e] = v1u.f[3 * e + k1] * v2[k2] - v1u.f[3 * e + k2] * v2[k1];
      }
      union { unsigned short h[8]; int4 v; } pk;
#pragma unroll
      for (int e = 0; e < 8; ++e) pk.h[e] = f2bf(t[e]);
      ldsT[addr] = pk.v;
    }
  }
  // ---- T0: seg 0..1 ; row = zl
#pragma unroll
  for (int sg = 0; sg < 2; ++sg) {
    int kt = sg * 4 + kq;
    int fl = (((lh << 4) | zl) ^ (kt & 7)) ^ lh;
    int addr = T0BASE + kt * 64 + fl;
    float t[8];
    if (sg == 0) {                       // s1 * s2         (-> W1)
#pragma unroll
      for (int e = 0; e < 8; ++e) t[e] = s1u.f[e] * s2;
    } else {                             // v1 . v2         (-> W4)
#pragma unroll
      for (int e = 0; e < 8; ++e) {
        const float* p = v1u.f + 3 * e;
        t[e] = p[0] * v2[0] + p[1] * v2[1] + p[2] * v2[2];
      }
    }
    union { unsigned short h[8]; int4 v; } pk;
#pragma unroll
    for (int e = 0; e < 8; ++e) pk.h[e] = f2bf(t[e]);
    ldsT[addr] = pk.v;
  }
}

static __device__ __forceinline__ void gemm_chunk(
    int c, int lane, int wid, const int4* ldsT,
    const int4* __restrict__ B1v, const int4* __restrict__ B0v,
    f32x4 acc1[3][4], f32x4 acc0[4])
{
  // ---- GEMM out1: 12 K-steps, reg double-buffered A (LDS) + B (L2)
  {
    int4 a[3], b[4];
    {
      int fl = lane ^ (lane >> 4);
      a[0] = ldsT[0 * 768 + fl];
      a[1] = ldsT[1 * 768 + fl];
      a[2] = ldsT[2 * 768 + fl];
      const int4* bp = B1v + ((size_t)(c * 12) * 16 + wid * 4) * 64 + lane;
      b[0] = bp[0]; b[1] = bp[64]; b[2] = bp[128]; b[3] = bp[192];
    }
#pragma unroll 1
    for (int kt = 0; kt < 12; ++kt) {
      int4 an[3], bn[4];
      if (kt < 11) {
        int fl = (lane ^ ((kt + 1) & 7)) ^ (lane >> 4);
        an[0] = ldsT[0 * 768 + (kt + 1) * 64 + fl];
        an[1] = ldsT[1 * 768 + (kt + 1) * 64 + fl];
        an[2] = ldsT[2 * 768 + (kt + 1) * 64 + fl];
        const int4* np = B1v + ((size_t)(c * 12 + kt + 1) * 16 + wid * 4) * 64 + lane;
        bn[0] = np[0]; bn[1] = np[64]; bn[2] = np[128]; bn[3] = np[192];
      } else {
        an[0] = a[0]; an[1] = a[1]; an[2] = a[2];
        bn[0] = b[0]; bn[1] = b[1]; bn[2] = b[2]; bn[3] = b[3];
      }
#pragma unroll
      for (int i = 0; i < 3; ++i) {
        bf16x8 av = asbf(a[i]);
#pragma unroll
        for (int j = 0; j < 4; ++j)
          acc1[i][j] = __builtin_amdgcn_mfma_f32_16x16x32_bf16(
              av, asbf(b[j]), acc1[i][j], 0, 0, 0);
      }
      a[0] = an[0]; a[1] = an[1]; a[2] = an[2];
      b[0] = bn[0]; b[1] = bn[1]; b[2] = bn[2]; b[3] = bn[3];
    }
  }
  // ---- GEMM out0: 8 K-steps
  {
    int4 a0, b[4];
    {
      int fl = lane ^ (lane >> 4);
      a0 = ldsT[T0BASE + fl];
      const int4* bp = B0v + ((size_t)(c * 8) * 16 + wid * 4) * 64 + lane;
      b[0] = bp[0]; b[1] = bp[64]; b[2] = bp[128]; b[3] = bp[192];
    }
#pragma unroll 1
    for (int kt = 0; kt < 8; ++kt) {
      int4 an, bn[4];
      if (kt < 7) {
        int fl = (lane ^ ((kt + 1) & 7)) ^ (lane >> 4);
        an = ldsT[T0BASE + (kt + 1) * 64 + fl];
        const int4* np = B0v + ((size_t)(c * 8 + kt + 1) * 16 + wid * 4) * 64 + lane;
        bn[0] = np[0]; bn[1] = np[64]; bn[2] = np[128]; bn[3] = np[192];
      } else {
        an = a0; bn[0] = b[0]; bn[1] = b[1]; bn[2] = b[2]; bn[3] = b[3];
      }
      bf16x8 av = asbf(a0);
#pragma unroll
      for (int j = 0; j < 4; ++j)
        acc0[j] = __builtin_amdgcn_mfma_f32_16x16x32_bf16(
            av, asbf(b[j]), acc0[j], 0, 0, 0);
      a0 = an; b[0] = bn[0]; b[1] = bn[1]; b[2] = bn[2]; b[3] = bn[3];
    }
  }
}

// ---------------------------------------------------------------------------
// Main kernel: 16 z-rows per block, 256 threads (4 waves), full 256 out-cols.
// LDS = 2816 int4 = 45 KB, 2 u-chunks of 128. Odd blocks process chunks in
// reversed order (phase/address diversity).
// ---------------------------------------------------------------------------
__global__ __launch_bounds__(256, 3) void tp_main(
    const float* __restrict__ x1, const float* __restrict__ x2,
    const int4* __restrict__ B1v, const int4* __restrict__ B0v,
    float* __restrict__ out)
{
  __shared__ int4 ldsT[2816];           // 45056 bytes
  const int tid  = threadIdx.x;
  const int lane = tid & 63;
  const int wid  = tid >> 6;            // wave = output col-quarter
  const int z0   = blockIdx.x * 16;
  const int zl   = tid >> 4;            // T-build row ownership
  const int rr   = tid & 15;            // T-build u-run ownership
  const int cA   = blockIdx.x & 1;      // first chunk (0 or 1)
  const int cB   = cA ^ 1;              // second chunk

  f32x4 acc1[3][4];
  f32x4 acc0[4];
#pragma unroll
  for (int i = 0; i < 3; ++i)
#pragma unroll
    for (int j = 0; j < 4; ++j) acc1[i][j] = (f32x4){0.f, 0.f, 0.f, 0.f};
#pragma unroll
  for (int j = 0; j < 4; ++j) acc0[j] = (f32x4){0.f, 0.f, 0.f, 0.f};

  // x2 row values (broadcast per 16 threads)
  float4 x2v = ((const float4*)x2)[z0 + zl];
  const float s2 = x2v.x;
  float v2[3] = {x2v.y, x2v.z, x2v.w};

  // issue ALL x1 loads up front (nt): second chunk's 8 dwordx4 stay in
  // flight under build-0 + GEMM-0 (compiler tracks vmcnt counts).
  X1Regs r0, r1;
  load_x1(r0, x1, z0 + zl, cA * 128, rr);
  load_x1(r1, x1, z0 + zl, cB * 128, rr);

  build_frags(r0, zl, rr, s2, v2, ldsT);
  __syncthreads();
  gemm_chunk(cA, lane, wid, ldsT, B1v, B0v, acc1, acc0);
  __syncthreads();
  build_frags(r1, zl, rr, s2, v2, ldsT);
  __syncthreads();
  gemm_chunk(cB, lane, wid, ldsT, B1v, B0v, acc1, acc0);

  // ---- epilogue: accumulators are the final outputs
  const int col = lane & 15;
  const int rb  = (lane >> 4) * 4;       // C/D: col=lane&15, row=(lane>>4)*4+reg
#pragma unroll
  for (int j = 0; j < 4; ++j) {
    int w = (wid * 4 + j) * 16 + col;
#pragma unroll
    for (int rg = 0; rg < 4; ++rg) {
      int row = rb + rg;                 // zl
      out[(size_t)(z0 + row) * 1024 + w] = acc0[j][rg];
    }
  }
#pragma unroll
  for (int i = 0; i < 3; ++i) {
#pragma unroll
    for (int j = 0; j < 4; ++j) {
      int w = (wid * 4 + j) * 16 + col;
#pragma unroll
      for (int rg = 0; rg < 4; ++rg) {
        int row = i * 16 + rb + rg;      // 0..47 ; row = 3*zl + k
        int zz = row / 3;
        int k  = row - zz * 3;
        out[(size_t)(z0 + zz) * 1024 + 256 + w * 3 + k] = acc1[i][j][rg];
      }
    }
  }
}

// ---------------------------------------------------------------------------
extern "C" void kernel_launch(void* const* d_in, const int* in_sizes, int n_in,
                              void* d_out, int out_size, void* d_ws, size_t ws_size,
                              hipStream_t stream) {
  const float* x1  = (const float*)d_in[0];   // (n, 1024) f32
  const float* x2  = (const float*)d_in[1];   // (n, 4)    f32
  const float* wgt = (const float*)d_in[2];   // (327680,) f32
  float* out = (float*)d_out;                 // (n, 1024) f32

  // ws: B1 fragments [0, 393216) + B0 fragments [393216, 655360)  (bf16)
  unsigned short* Bw = (unsigned short*)d_ws;
  const int4* B1v = (const int4*)Bw;
  const int4* B0v = B1v + 24576;

  int n = in_sizes[0] / 1024;                 // 20000 (divisible by 16)

  prep_weights<<<160, 256, 0, stream>>>(wgt, Bw);
  tp_main<<<n / 16, 256, 0, stream>>>(x1, x2, B1v, B0v, out);
}

// Round 10
// 73.782 us; speedup vs baseline: 1.2473x; 1.2473x over previous
//
#include <hip/hip_runtime.h>

// Simple_TensorProduct (e3nn uvw TP, MUL=256, l<=1, v=1) as two fused bf16 GEMMs.
//   out0[z,w]      = sum_k T0[z,k]    * B0[k,w]   (K=512)
//   out1[(z,c),w]  = sum_k T1[(z,c),k]* B1[k,w]   (K=768, M=3N)
// T = x1 with x2 folded in (built per z-tile, bf16, LDS, A-fragment order).
// B = weights, prescaled by path alphas, bf16, B-fragment order in d_ws.
//
// R10: compiler-proof software pipeline. All x1/B loads are asm volatile
// global_load_dwordx4 (un-sinkable, outputs forced live) with hand-counted
// s_waitcnt vmcnt(N) + sched_barrier(0) fences; barriers are raw
// lgkmcnt(0)+s_barrier so no compiler vmcnt(0) drain kills the cross-phase
// prefetch. Geometry/math identical to R7 (passed): 256 thr, z=16, w-half
// per block (grid 2500), u=64 x 4 chunks, ct=2/wave, dbuf LDS 22.5 KB.
// Phase c: burst B(c)[10] ; issue x1(c+2)[4] ; vmcnt(x1(c+1) done) ;
//          build(c+1) ; vmcnt(B done) ; gemm(c) pure LDS+MFMA ; barrier.

typedef short bf16x8 __attribute__((ext_vector_type(8)));
typedef float f32x4 __attribute__((ext_vector_type(4)));
typedef int   ni4   __attribute__((ext_vector_type(4)));

static __device__ __forceinline__ unsigned short f2bf(float f) {
  unsigned int u = __builtin_bit_cast(unsigned int, f);
  u += 0x7FFFu + ((u >> 16) & 1u);   // RNE
  return (unsigned short)(u >> 16);
}

static __device__ __forceinline__ bf16x8 asbf(int4 v) {
  return __builtin_bit_cast(bf16x8, v);
}
static __device__ __forceinline__ bf16x8 asbfn(ni4 v) {
  return __builtin_bit_cast(bf16x8, v);
}

static __device__ __forceinline__ void gload4(ni4& dst, const void* p) {
  asm volatile("global_load_dwordx4 %0, %1, off" : "=v"(dst) : "v"(p));
}

#define WAITV(n) do { \
    asm volatile("s_waitcnt vmcnt(" #n ")"); \
    __builtin_amdgcn_sched_barrier(0); \
  } while (0)

static __device__ __forceinline__ void phase_barrier() {
  __builtin_amdgcn_sched_barrier(0);
  asm volatile("s_waitcnt lgkmcnt(0)");
  __builtin_amdgcn_sched_barrier(0);
  __builtin_amdgcn_s_barrier();
  __builtin_amdgcn_sched_barrier(0);
}

// ---------------------------------------------------------------------------
// Weight prep (u-chunk = 64, c in 0..3; layout as passing R3/R4/R7):
// B1: fid = ((c*6+kt)*16+ct)*64+lane; elem e: kc=kt*32+(lane>>4)*8+e (0..191),
//     seg=kc>>6, u=c*64+(kc&63), w=ct*16+(lane&15)
// B0: fid = 24576 + ((c*4+kt)*16+ct)*64+lane; kc 0..127, seg=kc>>6
// ---------------------------------------------------------------------------
__global__ __launch_bounds__(256) void prep_weights(
    const float* __restrict__ wgt, unsigned short* __restrict__ Bw)
{
  int fid = blockIdx.x * 256 + threadIdx.x;
  union { unsigned short h[8]; int4 v; } pk;
  if (fid < 24576) {
    int lane = fid & 63;
    int ct = (fid >> 6) & 15;
    int q = fid >> 10;            // 0..23 = c*6 + kt
    int kt = q % 6, c = q / 6;
    int w = ct * 16 + (lane & 15);
    int kh = (lane >> 4) * 8;
#pragma unroll
    for (int e = 0; e < 8; ++e) {
      int kc = kt * 32 + kh + e;       // 0..191
      int seg = kc >> 6;
      int u = c * 64 + (kc & 63);
      float s  = (seg == 2) ? 0.025515518153991442f : 0.03608439182435161f;
      int off  = (seg == 0) ? 65536 : (seg == 1 ? 131072 : 262144);
      pk.h[e] = f2bf(wgt[off + u * 256 + w] * s);
    }
    ((int4*)Bw)[fid] = pk.v;
  } else if (fid < 40960) {
    int f2 = fid - 24576;
    int lane = f2 & 63;
    int ct = (f2 >> 6) & 15;
    int q = f2 >> 10;             // 0..15 = c*4 + kt
    int kt = q & 3, c = q >> 2;
    int w = ct * 16 + (lane & 15);
    int kh = (lane >> 4) * 8;
#pragma unroll
    for (int e = 0; e < 8; ++e) {
      int kc = kt * 32 + kh + e;       // 0..127
      int seg = kc >> 6;
      int u = c * 64 + (kc & 63);
      float s  = (seg == 0) ? 0.04419417382415922f : 0.025515518153991442f;
      int off  = (seg == 0) ? 0 : 196608;
      pk.h[e] = f2bf(wgt[off + u * 256 + w] * s);
    }
    ((int4*)Bw)[fid] = pk.v;
  }
}

// Per-buffer LDS map (int4 slots): T1 rt*384 + kt*64 + perm (rt 0..2, kt 0..5)
//                                  T0 1152 + kt*64 + perm   (kt 0..3)
// Buffer b at slot offset b*1408. Total 2816 int4 = 45056 B... here 2x1408.
#define BUFSLOTS 1408
#define T0BASE 1152

struct X1Raw { ni4 a0, a1, a2, a3; };   // s1[4] + v1[4u x 3k] raw bits

static __device__ __forceinline__ void load_x1_asm(
    X1Raw& r, const float* __restrict__ x1, int zrow, int ub, int rr)
{
  const float* base = x1 + (size_t)zrow * 1024;
  gload4(r.a0, base + ub + rr * 4);
  const float* pv = base + 256 + 3 * ub + rr * 12;
  gload4(r.a1, pv);
  gload4(r.a2, pv + 4);
  gload4(r.a3, pv + 8);
}

// thread (zl 0..15, rr 0..15) owns u-run [rr*4, rr*4+4) of the 64-u chunk.
// kc = sg*64 + rr*4 + e -> kt = sg*2 + (rr>>3), lh = (rr>>1)&3, half = rr&1.
// (identical math to R7's passing build)
static __device__ __forceinline__ void build_frags(
    const X1Raw& r, int zl, int rr, float s2, const float* v2, int4* ldsT)
{
  union { float4 q; float f[4]; } s1u;
  s1u.q = __builtin_bit_cast(float4, r.a0);
  union { float4 q[3]; float f[12]; } v1u;
  v1u.q[0] = __builtin_bit_cast(float4, r.a1);
  v1u.q[1] = __builtin_bit_cast(float4, r.a2);
  v1u.q[2] = __builtin_bit_cast(float4, r.a3);
  const int lh   = (rr >> 1) & 3;
  const int kq   = rr >> 3;
  const int half = rr & 1;
  int2* lds2 = (int2*)ldsT;

  // ---- T1: seg 0..2 x comp k 0..2 ; row = 3*zl + k (0..47)
#pragma unroll
  for (int sg = 0; sg < 3; ++sg) {
#pragma unroll
    for (int k = 0; k < 3; ++k) {
      int row = 3 * zl + k;
      int kt  = sg * 2 + kq;
      int fl  = (((lh << 4) | (row & 15)) ^ (kt & 7)) ^ lh;
      int slot = (row >> 4) * 384 + kt * 64 + fl;
      float t[4];
      if (sg == 0) {                     // s1 * v2[k]      (-> W2)
#pragma unroll
        for (int e = 0; e < 4; ++e) t[e] = s1u.f[e] * v2[k];
      } else if (sg == 1) {              // v1[.,k] * s2    (-> W3)
#pragma unroll
        for (int e = 0; e < 4; ++e) t[e] = v1u.f[3 * e + k] * s2;
      } else {                           // (v1 x v2)[k]    (-> W5)
        int k1 = k + 1; if (k1 > 2) k1 -= 3;
        int k2 = k + 2; if (k2 > 2) k2 -= 3;
#pragma unroll
        for (int e = 0; e < 4; ++e)
          t[e] = v1u.f[3 * e + k1] * v2[k2] - v1u.f[3 * e + k2] * v2[k1];
      }
      union { unsigned short h[4]; int2 v; } pk;
#pragma unroll
      for (int e = 0; e < 4; ++e) pk.h[e] = f2bf(t[e]);
      lds2[slot * 2 + half] = pk.v;
    }
  }
  // ---- T0: seg 0..1 ; row = zl (0..15)
#pragma unroll
  for (int sg = 0; sg < 2; ++sg) {
    int kt = sg * 2 + kq;
    int fl = (((lh << 4) | zl) ^ (kt & 7)) ^ lh;
    int slot = T0BASE + kt * 64 + fl;
    float t[4];
    if (sg == 0) {                       // s1 * s2         (-> W1)
#pragma unroll
      for (int e = 0; e < 4; ++e) t[e] = s1u.f[e] * s2;
    } else {                             // v1 . v2         (-> W4)
#pragma unroll
      for (int e = 0; e < 4; ++e)
        t[e] = v1u.f[3 * e] * v2[0] + v1u.f[3 * e + 1] * v2[1]
             + v1u.f[3 * e + 2] * v2[2];
    }
    union { unsigned short h[4]; int2 v; } pk;
#pragma unroll
    for (int e = 0; e < 4; ++e) pk.h[e] = f2bf(t[e]);
    lds2[slot * 2 + half] = pk.v;
  }
}

// Burst-load this wave's ENTIRE per-chunk B slice as asm: 20 int4 (80 VGPR).
// vb[0..11] = out1 kt 0..5 x {ct0, ct0+1}; vb[12..19] = out0 kt 0..3.
static __device__ __forceinline__ void burstB(
    ni4 (&vb)[20], const int4* __restrict__ B1v,
    const int4* __restrict__ B0v, int c, int ct0, int lane)
{
#pragma unroll
  for (int s = 0; s < 6; ++s) {
    const int4* p = B1v + ((size_t)((c * 6 + s) * 16 + ct0)) * 64 + lane;
    gload4(vb[s * 2],     p);
    gload4(vb[s * 2 + 1], p + 64);
  }
#pragma unroll
  for (int s = 0; s < 4; ++s) {
    const int4* p = B0v + ((size_t)((c * 4 + s) * 16 + ct0)) * 64 + lane;
    gload4(vb[12 + s * 2],     p);
    gload4(vb[12 + s * 2 + 1], p + 64);
  }
}

// Pure LDS+MFMA gemm for one u-chunk (no global loads). Identical to R7.
static __device__ __forceinline__ void gemm_steps(
    const int4* __restrict__ buf, const ni4 (&vb)[20], int lane,
    f32x4 acc1[3][2], f32x4 acc0[2])
{
#pragma unroll
  for (int kt = 0; kt < 6; ++kt) {
    int fl = (lane ^ (kt & 7)) ^ (lane >> 4);
    int4 a0 = buf[kt * 64 + fl];
    int4 a1 = buf[384 + kt * 64 + fl];
    int4 a2 = buf[768 + kt * 64 + fl];
    int4 a[3] = {a0, a1, a2};
#pragma unroll
    for (int rt = 0; rt < 3; ++rt) {
      bf16x8 av = asbf(a[rt]);
#pragma unroll
      for (int j = 0; j < 2; ++j)
        acc1[rt][j] = __builtin_amdgcn_mfma_f32_16x16x32_bf16(
            av, asbfn(vb[kt * 2 + j]), acc1[rt][j], 0, 0, 0);
    }
  }
#pragma unroll
  for (int kt = 0; kt < 4; ++kt) {
    int fl = (lane ^ (kt & 7)) ^ (lane >> 4);
    int4 a0 = buf[T0BASE + kt * 64 + fl];
    bf16x8 av = asbf(a0);
#pragma unroll
    for (int j = 0; j < 2; ++j)
      acc0[j] = __builtin_amdgcn_mfma_f32_16x16x32_bf16(
          av, asbfn(vb[12 + kt * 2 + j]), acc0[j], 0, 0, 0);
  }
}

// ---------------------------------------------------------------------------
// Main: 256 threads (4 waves, ct=2 each -> 128 cols), w-split across 2 blocks
// per z-tile (grid 2500). 16 z-rows, 4 u-chunks of 64, double-buffered LDS.
// ---------------------------------------------------------------------------
__global__ __launch_bounds__(256, 2) void tp_main(
    const float* __restrict__ x1, const float* __restrict__ x2,
    const int4* __restrict__ B1v, const int4* __restrict__ B0v,
    float* __restrict__ out)
{
  __shared__ int4 ldsT[2 * BUFSLOTS];   // 45056 bytes
  const int tid  = threadIdx.x;
  const int lane = tid & 63;
  const int wid  = tid >> 6;            // wave 0..3
  const int wh   = blockIdx.x & 1;      // w-half
  const int ct0  = wh * 8 + wid * 2;    // this wave's two 16-col tiles (global)
  const int z0   = (blockIdx.x >> 1) * 16;
  const int zl   = tid >> 4;            // T-build row (0..15)
  const int rr   = tid & 15;            // T-build u-run (0..15)

  f32x4 acc1[3][2];
  f32x4 acc0[2];
#pragma unroll
  for (int i = 0; i < 3; ++i)
#pragma unroll
    for (int j = 0; j < 2; ++j) acc1[i][j] = (f32x4){0.f, 0.f, 0.f, 0.f};
#pragma unroll
  for (int j = 0; j < 2; ++j) acc0[j] = (f32x4){0.f, 0.f, 0.f, 0.f};

  float4 x2v = ((const float4*)x2)[z0 + zl];   // normal load (compiler-waited)
  const float s2 = x2v.x;
  float v2[3] = {x2v.y, x2v.z, x2v.w};

  X1Raw rA, rB;
  ni4 vb[20];

  // prologue: x1(0)->rA, x1(1)->rB in flight (8 outstanding)
  load_x1_asm(rA, x1, z0 + zl, 0, rr);
  load_x1_asm(rB, x1, z0 + zl, 64, rr);
  WAITV(4);                              // x1(0) done, x1(1) in flight
  build_frags(rA, zl, rr, s2, v2, ldsT);
  phase_barrier();

  // ---- phase 0: gemm(0,buf0) ; build(1)->buf1 ; x1(2)->rA
  burstB(vb, B1v, B0v, 0, ct0, lane);    // out: 4 + 10 = 14
  load_x1_asm(rA, x1, z0 + zl, 128, rr); // out: 18
  WAITV(14);                             // x1(1) done
  build_frags(rB, zl, rr, s2, v2, ldsT + BUFSLOTS);
  WAITV(4);                              // B(0) done, x1(2) in flight
  gemm_steps(ldsT, vb, lane, acc1, acc0);
  phase_barrier();

  // ---- phase 1: gemm(1,buf1) ; build(2)->buf0 ; x1(3)->rB
  burstB(vb, B1v, B0v, 1, ct0, lane);    // out: 4 + 10 = 14
  load_x1_asm(rB, x1, z0 + zl, 192, rr); // out: 18
  WAITV(14);                             // x1(2) done
  build_frags(rA, zl, rr, s2, v2, ldsT);
  WAITV(4);                              // B(1) done, x1(3) in flight
  gemm_steps(ldsT + BUFSLOTS, vb, lane, acc1, acc0);
  phase_barrier();

  // ---- phase 2: gemm(2,buf0) ; build(3)->buf1
  burstB(vb, B1v, B0v, 2, ct0, lane);    // out: 4 + 10 = 14
  WAITV(10);                             // x1(3) done
  build_frags(rB, zl, rr, s2, v2, ldsT + BUFSLOTS);
  WAITV(0);                              // B(2) done
  gemm_steps(ldsT, vb, lane, acc1, acc0);
  phase_barrier();

  // ---- phase 3: gemm(3,buf1)
  burstB(vb, B1v, B0v, 3, ct0, lane);    // out: 10
  WAITV(0);                              // B(3) done
  gemm_steps(ldsT + BUFSLOTS, vb, lane, acc1, acc0);

  // ---- epilogue: accumulators are the final outputs
  const int col = lane & 15;
  const int rb  = (lane >> 4) * 4;       // C/D: col=lane&15, row=(lane>>4)*4+reg
#pragma unroll
  for (int j = 0; j < 2; ++j) {
    int w = (ct0 + j) * 16 + col;
#pragma unroll
    for (int rg = 0; rg < 4; ++rg) {
      int row = rb + rg;                 // zl 0..15
      out[(size_t)(z0 + row) * 1024 + w] = acc0[j][rg];
    }
  }
#pragma unroll
  for (int rt = 0; rt < 3; ++rt) {
#pragma unroll
    for (int j = 0; j < 2; ++j) {
      int w = (ct0 + j) * 16 + col;
#pragma unroll
      for (int rg = 0; rg < 4; ++rg) {
        int row = rt * 16 + rb + rg;     // 0..47 ; row = 3*zl + k
        int zz = row / 3;
        int k  = row - zz * 3;
        out[(size_t)(z0 + zz) * 1024 + 256 + w * 3 + k] = acc1[rt][j][rg];
      }
    }
  }
}

// ---------------------------------------------------------------------------
extern "C" void kernel_launch(void* const* d_in, const int* in_sizes, int n_in,
                              void* d_out, int out_size, void* d_ws, size_t ws_size,
                              hipStream_t stream) {
  const float* x1  = (const float*)d_in[0];   // (n, 1024) f32
  const float* x2  = (const float*)d_in[1];   // (n, 4)    f32
  const float* wgt = (const float*)d_in[2];   // (327680,) f32
  float* out = (float*)d_out;                 // (n, 1024) f32

  // ws: B1 fragments [0, 393216) + B0 fragments [393216, 655360)  (bf16)
  unsigned short* Bw = (unsigned short*)d_ws;
  const int4* B1v = (const int4*)Bw;
  const int4* B0v = B1v + 24576;

  int n = in_sizes[0] / 1024;                 // 20000 (divisible by 16)

  prep_weights<<<160, 256, 0, stream>>>(wgt, Bw);
  tp_main<<<(n / 16) * 2, 256, 0, stream>>>(x1, x2, B1v, B0v, out);
}